// Round 2
// baseline (370.088 us; speedup 1.0000x reference)
//
#include <hip/hip_runtime.h>
#include <math.h>

// Fast guided filter, fully fused single kernel — FP64 internal math.
// The harness reference ("np") is float64; fp32 internal math flips argmin
// near-ties (round-1 absmax=8.0 > 5.1). All arithmetic after the (exact)
// fp32 input loads is done in double so tie decisions match the reference.
//
// Output(y,x) depends on 5x5 input neighborhood:
//   stage (TY+4)x(TX+4) inputs (replicate-clamped) -> LDS (fp32, exact)
//   compute A,b on (TY+2)x(TX+2) in fp64 (zero outside image) -> LDS (fp64)
//   8 directional 3x3 convs + argmin + trunc/clamp in fp64 -> global fp32

#define TX 64
#define TY 16
#define SW (TX + 4)   // 68
#define SH (TY + 4)   // 20
#define AW (TX + 2)   // 66
#define AH (TY + 2)   // 18
#define NT 256

__global__ __launch_bounds__(NT) void fgf_fused_kernel(
    const float* __restrict__ x, const float* __restrict__ y,
    float* __restrict__ out, int H, int W)
{
    __shared__ float  sx[SH][SW];
    __shared__ float  sy[SH][SW];
    __shared__ double sA[AH][AW];
    __shared__ double sB[AH][AW];

    const int c   = blockIdx.z;
    const int ox0 = blockIdx.x * TX;
    const int oy0 = blockIdx.y * TY;
    const size_t plane = (size_t)H * (size_t)W;
    const float* xc = x + (size_t)c * plane;
    const float* yc = y + (size_t)c * plane;

    const int tid = threadIdx.y * 64 + threadIdx.x;

    // ---- stage inputs with replicate clamp (box filter uses edge pad) ----
    for (int i = tid; i < SH * SW; i += NT) {
        int ly = i / SW, lx = i - ly * SW;
        int gy = oy0 - 2 + ly;
        int gx = ox0 - 2 + lx;
        gy = gy < 0 ? 0 : (gy >= H ? H - 1 : gy);
        gx = gx < 0 ? 0 : (gx >= W ? W - 1 : gx);
        size_t gidx = (size_t)gy * W + gx;
        sx[ly][lx] = xc[gidx];
        sy[ly][lx] = yc[gidx];
    }
    __syncthreads();

    // ---- A,b on (TY+2)x(TX+2) in fp64; zero outside image (zero pad for dir conv) ----
    const double inv9 = 1.0 / 9.0;
    for (int i = tid; i < AH * AW; i += NT) {
        int ly = i / AW, lx = i - ly * AW;
        int ay = oy0 - 1 + ly;
        int ax = ox0 - 1 + lx;
        double Av = 0.0, Bv = 0.0;
        if (ay >= 0 && ay < H && ax >= 0 && ax < W) {
            double sumx = 0.0, sumy = 0.0, sumxy = 0.0, sumxx = 0.0;
#pragma unroll
            for (int dy = 0; dy < 3; dy++) {
#pragma unroll
                for (int dx = 0; dx < 3; dx++) {
                    double xv = (double)sx[ly + dy][lx + dx];
                    double yv = (double)sy[ly + dy][lx + dx];
                    sumx  += xv;
                    sumy  += yv;
                    sumxy += xv * yv;
                    sumxx += xv * xv;
                }
            }
            double mx  = sumx * inv9;
            double my  = sumy * inv9;
            double cov = sumxy * inv9 - mx * my;
            double var = sumxx * inv9 - mx * mx;
            Av = cov / (var + 1e-4);
            Bv = my - Av * mx;
        }
        sA[ly][lx] = Av;
        sB[ly][lx] = Bv;
    }
    __syncthreads();

    // ---- directional convs + argmin in fp64 ----
    const double i6 = 1.0 / 6.0;
    const int tx = threadIdx.x;           // 0..63
    for (int ry = threadIdx.y; ry < TY; ry += 4) {
        int yg = oy0 + ry;
        int xg = ox0 + tx;
        if (yg >= H || xg >= W) continue;

        // A,b 3x3 neighborhood; A-origin is (oy0-1, ox0-1) -> local (ry+dy, tx+dx)
        double a00 = sA[ry + 0][tx + 0], a01 = sA[ry + 0][tx + 1], a02 = sA[ry + 0][tx + 2];
        double a10 = sA[ry + 1][tx + 0], a11 = sA[ry + 1][tx + 1], a12 = sA[ry + 1][tx + 2];
        double a20 = sA[ry + 2][tx + 0], a21 = sA[ry + 2][tx + 1], a22 = sA[ry + 2][tx + 2];
        double b00 = sB[ry + 0][tx + 0], b01 = sB[ry + 0][tx + 1], b02 = sB[ry + 0][tx + 2];
        double b10 = sB[ry + 1][tx + 0], b11 = sB[ry + 1][tx + 1], b12 = sB[ry + 1][tx + 2];
        double b20 = sB[ry + 2][tx + 0], b21 = sB[ry + 2][tx + 1], b22 = sB[ry + 2][tx + 2];

        // row partials: t = rows 0+1, m = rows 1+2, c = all 3 rows (per column)
        double at0 = a00 + a10, at1 = a01 + a11, at2 = a02 + a12;
        double am0 = a10 + a20, am1 = a11 + a21, am2 = a12 + a22;
        double ac0 = at0 + a20, ac1 = at1 + a21, ac2 = at2 + a22;
        double bt0 = b00 + b10, bt1 = b01 + b11, bt2 = b02 + b12;
        double bm0 = b10 + b20, bm1 = b11 + b21, bm2 = b12 + b22;
        double bc0 = bt0 + b20, bc1 = bt1 + b21, bc2 = bt2 + b22;

        // directions in reference stack order: L, R, U, D, NW, NE, SW, SE
        double cA[8], cB[8];
        cA[0] = (ac0 + ac1) * i6;        cB[0] = (bc0 + bc1) * i6;
        cA[1] = (ac1 + ac2) * i6;        cB[1] = (bc1 + bc2) * i6;
        cA[2] = (at0 + at1 + at2) * i6;  cB[2] = (bt0 + bt1 + bt2) * i6;
        cA[3] = (am0 + am1 + am2) * i6;  cB[3] = (bm0 + bm1 + bm2) * i6;
        cA[4] = (at0 + at1) * 0.25;      cB[4] = (bt0 + bt1) * 0.25;
        cA[5] = (at1 + at2) * 0.25;      cB[5] = (bt1 + bt2) * 0.25;
        cA[6] = (am0 + am1) * 0.25;      cB[6] = (bm0 + bm1) * 0.25;
        cA[7] = (am1 + am2) * 0.25;      cB[7] = (bm1 + bm2) * 0.25;

        double im = (double)sx[ry + 2][tx + 2];   // original lr_x at output pixel

        // sequential argmin over |d|, strict < keeps first index (argmin tie rule)
        double best_ad = 1.0e300;
        double best_d  = 0.0;
#pragma unroll
        for (int k = 0; k < 8; k++) {
            double d  = cA[k] * im + cB[k] - im;
            double ad = fabs(d);
            if (ad < best_ad) { best_ad = ad; best_d = d; }
        }

        double res = trunc(best_d + im);
        res = fmin(fmax(res, 0.0), 255.0);
        out[(size_t)c * plane + (size_t)yg * W + xg] = (float)res;
    }
}

extern "C" void kernel_launch(void* const* d_in, const int* in_sizes, int n_in,
                              void* d_out, int out_size, void* d_ws, size_t ws_size,
                              hipStream_t stream) {
    const float* lr_x = (const float*)d_in[0];
    const float* lr_y = (const float*)d_in[1];
    // d_in[2] (hr_x) is never used by the reference computation.
    float* out = (float*)d_out;

    const int plane = in_sizes[0] / 3;
    const int H = (int)(0.5 + sqrt((double)plane));
    const int W = plane / H;

    dim3 block(64, 4, 1);
    dim3 grid((W + TX - 1) / TX, (H + TY - 1) / TY, 3);
    fgf_fused_kernel<<<grid, block, 0, stream>>>(lr_x, lr_y, out, H, W);
}

// Round 3
// 357.720 us; speedup vs baseline: 1.0346x; 1.0346x over previous
//
#include <hip/hip_runtime.h>
#include <math.h>

// Fast guided filter, fully fused, FP64 internal math (matches fp64 "np" ref).
// Round-3 changes vs round-2 (127 us, VALUBusy 75% -> fp64-VALU-bound):
//   1. fp64 IEEE div -> v_rcp_f64 + 2 Newton steps (~1 ulp, no argmin-flip risk)
//   2. stage 2 scaled-sum algebra: A = (9Sxy - Sx*Sy)/(9Sxx - Sx^2 + 81eps),
//      b = (Sy - A*Sx)/9  (removes mean normalizations)
//   3. stage 3 vertical sliding window: 4 contiguous rows/thread, 6 ds_read_b64
//      per advance instead of 18 per pixel; row-pair partials reused in regs.

#define TX 64
#define TY 16
#define SW (TX + 4)   // 68
#define SH (TY + 4)   // 20
#define AW (TX + 2)   // 66
#define AH (TY + 2)   // 18
#define NT 256

__device__ __forceinline__ double fast_rcp(double v) {
#if __has_builtin(__builtin_amdgcn_rcp)
    double r = __builtin_amdgcn_rcp(v);     // v_rcp_f64, ~29-bit
#else
    double r = 1.0 / v;
#endif
    double e = fma(-v, r, 1.0);             // Newton 1 -> ~53-bit
    r = fma(r, e, r);
    e = fma(-v, r, 1.0);                    // Newton 2 -> ~1 ulp
    r = fma(r, e, r);
    return r;
}

__global__ __launch_bounds__(NT) void fgf_fused_kernel(
    const float* __restrict__ x, const float* __restrict__ y,
    float* __restrict__ out, int H, int W)
{
    __shared__ float  sxs[SH][SW];
    __shared__ float  sys[SH][SW];
    __shared__ double sA[AH][AW];
    __shared__ double sB[AH][AW];

    const int c   = blockIdx.z;
    const int ox0 = blockIdx.x * TX;
    const int oy0 = blockIdx.y * TY;
    const size_t plane = (size_t)H * (size_t)W;
    const float* xc = x + (size_t)c * plane;
    const float* yc = y + (size_t)c * plane;

    const int tid = threadIdx.y * 64 + threadIdx.x;

    // ---- stage 1: inputs with replicate clamp (box filter uses edge pad) ----
    for (int i = tid; i < SH * SW; i += NT) {
        int ly = i / SW, lx = i - ly * SW;
        int gy = oy0 - 2 + ly;
        int gx = ox0 - 2 + lx;
        gy = gy < 0 ? 0 : (gy >= H ? H - 1 : gy);
        gx = gx < 0 ? 0 : (gx >= W ? W - 1 : gx);
        size_t gidx = (size_t)gy * W + gx;
        sxs[ly][lx] = xc[gidx];
        sys[ly][lx] = yc[gidx];
    }
    __syncthreads();

    // ---- stage 2: A,b on (TY+2)x(TX+2) in fp64; zero outside image ----
    const double EPS81 = 81.0 * 1.0e-4;
    const double INV9  = 1.0 / 9.0;
    for (int i = tid; i < AH * AW; i += NT) {
        int ly = i / AW, lx = i - ly * AW;
        int ay = oy0 - 1 + ly;
        int ax = ox0 - 1 + lx;
        double Av = 0.0, Bv = 0.0;
        if (ay >= 0 && ay < H && ax >= 0 && ax < W) {
            double sx4 = 0.0, sy4 = 0.0, sxy = 0.0, sxx = 0.0;
#pragma unroll
            for (int dy = 0; dy < 3; dy++) {
#pragma unroll
                for (int dx = 0; dx < 3; dx++) {
                    double xv = (double)sxs[ly + dy][lx + dx];
                    double yv = (double)sys[ly + dy][lx + dx];
                    sx4 += xv;
                    sy4 += yv;
                    sxy = fma(xv, yv, sxy);
                    sxx = fma(xv, xv, sxx);
                }
            }
            double num = fma(-sx4, sy4, 9.0 * sxy);            // 9*cov*9
            double den = fma(-sx4, sx4, fma(9.0, sxx, EPS81)); // 9*(var+eps)*9
            Av = num * fast_rcp(den);
            Bv = fma(-Av, sx4, sy4) * INV9;
        }
        sA[ly][lx] = Av;
        sB[ly][lx] = Bv;
    }
    __syncthreads();

    // ---- stage 3: sliding-window directional convs + argmin (fp64) ----
    // Thread handles column tx, output rows r0..r0+3 (contiguous).
    // Output row r uses A local rows r, r+1, r+2.
    const double I6 = 1.0 / 6.0;
    const int tx = threadIdx.x;          // 0..63
    const int g  = threadIdx.y;          // 0..3
    const int r0 = g * 4;
    const int xg = ox0 + tx;
    const bool xok = (xg < W);

    // per-column state: top = A[r-1..r]+.., mid = A[r..r+1], p = A[r+1] (local r+2)
    double tA[3], mA[3], pA[3], tB[3], mB[3], pB[3];
#pragma unroll
    for (int cc = 0; cc < 3; cc++) {
        double a0 = sA[r0 + 0][tx + cc];
        double a1 = sA[r0 + 1][tx + cc];
        double a2 = sA[r0 + 2][tx + cc];
        tA[cc] = a0 + a1; mA[cc] = a1 + a2; pA[cc] = a2;
        double b0 = sB[r0 + 0][tx + cc];
        double b1 = sB[r0 + 1][tx + cc];
        double b2 = sB[r0 + 2][tx + cc];
        tB[cc] = b0 + b1; mB[cc] = b1 + b2; pB[cc] = b2;
    }

#pragma unroll
    for (int step = 0; step < 4; step++) {
        const int r  = r0 + step;
        const int yg = oy0 + r;
        if (xok && yg < H) {
            // full_c = rows r-1..r+1 = top_c + p_c
            double fA0 = tA[0] + pA[0], fA1 = tA[1] + pA[1], fA2 = tA[2] + pA[2];
            double fB0 = tB[0] + pB[0], fB1 = tB[1] + pB[1], fB2 = tB[2] + pB[2];

            double t01A = tA[0] + tA[1], t12A = tA[1] + tA[2];
            double m01A = mA[0] + mA[1], m12A = mA[1] + mA[2];
            double t01B = tB[0] + tB[1], t12B = tB[1] + tB[2];
            double m01B = mB[0] + mB[1], m12B = mB[1] + mB[2];

            // L, R, U, D, NW, NE, SW, SE
            double cA[8], cB[8];
            cA[0] = (fA0 + fA1) * I6;      cB[0] = (fB0 + fB1) * I6;
            cA[1] = (fA1 + fA2) * I6;      cB[1] = (fB1 + fB2) * I6;
            cA[2] = (t01A + tA[2]) * I6;   cB[2] = (t01B + tB[2]) * I6;
            cA[3] = (m01A + mA[2]) * I6;   cB[3] = (m01B + mB[2]) * I6;
            cA[4] = t01A * 0.25;           cB[4] = t01B * 0.25;
            cA[5] = t12A * 0.25;           cB[5] = t12B * 0.25;
            cA[6] = m01A * 0.25;           cB[6] = m01B * 0.25;
            cA[7] = m12A * 0.25;           cB[7] = m12B * 0.25;

            double im = (double)sxs[r + 2][tx + 2];

            double best_ad = 1.0e300, best_d = 0.0;
#pragma unroll
            for (int k = 0; k < 8; k++) {
                double d  = fma(cA[k], im, cB[k]) - im;
                double ad = fabs(d);
                if (ad < best_ad) { best_ad = ad; best_d = d; }
            }

            double res = trunc(best_d + im);
            res = fmin(fmax(res, 0.0), 255.0);
            out[(size_t)c * plane + (size_t)yg * W + xg] = (float)res;
        }

        if (step < 3) {
            // advance: new A local row r+3
#pragma unroll
            for (int cc = 0; cc < 3; cc++) {
                double nA = sA[r0 + step + 3][tx + cc];
                double nB = sB[r0 + step + 3][tx + cc];
                tA[cc] = mA[cc]; mA[cc] = pA[cc] + nA; pA[cc] = nA;
                tB[cc] = mB[cc]; mB[cc] = pB[cc] + nB; pB[cc] = nB;
            }
        }
    }
}

extern "C" void kernel_launch(void* const* d_in, const int* in_sizes, int n_in,
                              void* d_out, int out_size, void* d_ws, size_t ws_size,
                              hipStream_t stream) {
    const float* lr_x = (const float*)d_in[0];
    const float* lr_y = (const float*)d_in[1];
    // d_in[2] (hr_x) is dead in the reference computation.
    float* out = (float*)d_out;

    const int plane = in_sizes[0] / 3;
    const int H = (int)(0.5 + sqrt((double)plane));
    const int W = plane / H;

    dim3 block(64, 4, 1);
    dim3 grid((W + TX - 1) / TX, (H + TY - 1) / TY, 3);
    fgf_fused_kernel<<<grid, block, 0, stream>>>(lr_x, lr_y, out, H, W);
}